// Round 1
// baseline (60.316 us; speedup 1.0000x reference)
//
#include <hip/hip_runtime.h>
#include <hip/hip_bf16.h>

// Problem constants (B=1, S=5, Q=512, T=64, D=2048)
#define S_DIM 5
#define Q_DIM 512
#define T_DIM 64
#define D_DIM 2048
#define EPS_CS 1e-8f

// Workspace layout (floats):
//   sp  : [S_DIM][D_DIM]          offset 0            (10240 floats)
//   sn  : [S_DIM] (padded to 8)   offset 10240        (8 floats)
//   num : [Q_DIM][S_DIM]          offset 10248        (2560 floats)
//   sq  : [Q_DIM]                 offset 12808        (512 floats)

__device__ __forceinline__ float wave_reduce_sum(float v) {
    #pragma unroll
    for (int off = 32; off > 0; off >>= 1)
        v += __shfl_down(v, off, 64);
    return v;
}

// Kernel 1: pool supp over T -> sp[s][d]; also sn[s] = ||sp[s]||.
// 5 blocks x 512 threads; thread owns float4 at d = tid*4.
__global__ __launch_bounds__(512) void supp_pool_kernel(
    const float* __restrict__ supp, float* __restrict__ sp, float* __restrict__ sn)
{
    const int s   = blockIdx.x;
    const int tid = threadIdx.x;
    const float4* base = (const float4*)(supp + (size_t)s * T_DIM * D_DIM);

    float4 acc = make_float4(0.f, 0.f, 0.f, 0.f);
    #pragma unroll 8
    for (int t = 0; t < T_DIM; ++t) {
        float4 v = base[t * (D_DIM / 4) + tid];
        acc.x += v.x; acc.y += v.y; acc.z += v.z; acc.w += v.w;
    }
    const float inv = 1.0f / (float)T_DIM;
    acc.x *= inv; acc.y *= inv; acc.z *= inv; acc.w *= inv;

    ((float4*)(sp + (size_t)s * D_DIM))[tid] = acc;

    float sq = acc.x * acc.x + acc.y * acc.y + acc.z * acc.z + acc.w * acc.w;
    float r = wave_reduce_sum(sq);

    __shared__ float lds[8];
    const int wave = tid >> 6, lane = tid & 63;
    if (lane == 0) lds[wave] = r;
    __syncthreads();
    if (tid == 0) {
        float tot = 0.f;
        #pragma unroll
        for (int w = 0; w < 8; ++w) tot += lds[w];
        sn[s] = sqrtf(tot);
    }
}

// Kernel 2: per-q: pool query over T in registers, dot vs the 5 sp rows,
// plus self-dot. 512 blocks x 512 threads; thread owns float4 at d = tid*4.
__global__ __launch_bounds__(512) void query_pool_dot_kernel(
    const float* __restrict__ query, const float* __restrict__ sp,
    float* __restrict__ num, float* __restrict__ sq)
{
    const int q   = blockIdx.x;
    const int tid = threadIdx.x;
    const float4* base = (const float4*)(query + (size_t)q * T_DIM * D_DIM);

    float4 acc = make_float4(0.f, 0.f, 0.f, 0.f);
    #pragma unroll 8
    for (int t = 0; t < T_DIM; ++t) {
        float4 v = base[t * (D_DIM / 4) + tid];
        acc.x += v.x; acc.y += v.y; acc.z += v.z; acc.w += v.w;
    }
    const float inv = 1.0f / (float)T_DIM;
    acc.x *= inv; acc.y *= inv; acc.z *= inv; acc.w *= inv;

    float vals[6];
    vals[5] = acc.x * acc.x + acc.y * acc.y + acc.z * acc.z + acc.w * acc.w;
    #pragma unroll
    for (int s = 0; s < S_DIM; ++s) {
        float4 sv = ((const float4*)(sp + (size_t)s * D_DIM))[tid];
        vals[s] = acc.x * sv.x + acc.y * sv.y + acc.z * sv.z + acc.w * sv.w;
    }

    __shared__ float lds[8][6];
    const int wave = tid >> 6, lane = tid & 63;
    #pragma unroll
    for (int k = 0; k < 6; ++k) {
        float r = wave_reduce_sum(vals[k]);
        if (lane == 0) lds[wave][k] = r;
    }
    __syncthreads();
    if (tid < 6) {
        float r = 0.f;
        #pragma unroll
        for (int w = 0; w < 8; ++w) r += lds[w][tid];
        if (tid < S_DIM) num[(size_t)q * S_DIM + tid] = r;
        else             sq[q] = r;
    }
}

// Kernel 3: dist, 1-dist output, log-softmax over S, NLL mean.
// 1 block x 512 threads (thread == q).
__global__ __launch_bounds__(512) void finalize_kernel(
    const float* __restrict__ num, const float* __restrict__ sq,
    const float* __restrict__ sn, const int* __restrict__ ys,
    float* __restrict__ out)
{
    const int q = threadIdx.x;

    const float qn = sqrtf(sq[q]);
    float dist[S_DIM];
    #pragma unroll
    for (int s = 0; s < S_DIM; ++s) {
        float d = num[(size_t)q * S_DIM + s] / fmaxf(qn * sn[s], EPS_CS);
        dist[s] = d;
        out[1 + (size_t)q * S_DIM + s] = 1.0f - d;
    }

    float m = dist[0];
    #pragma unroll
    for (int s = 1; s < S_DIM; ++s) m = fmaxf(m, dist[s]);
    float sum = 0.f;
    #pragma unroll
    for (int s = 0; s < S_DIM; ++s) sum += expf(dist[s] - m);
    const float lse = m + logf(sum);

    int y = ys[q];
    if (y < 0) y = 0; if (y >= S_DIM) y = S_DIM - 1;
    const float nll = lse - dist[y];

    float r = wave_reduce_sum(nll);
    __shared__ float lds[8];
    const int wave = q >> 6, lane = q & 63;
    if (lane == 0) lds[wave] = r;
    __syncthreads();
    if (q == 0) {
        float tot = 0.f;
        #pragma unroll
        for (int w = 0; w < 8; ++w) tot += lds[w];
        out[0] = tot * (1.0f / (float)Q_DIM);
    }
}

extern "C" void kernel_launch(void* const* d_in, const int* in_sizes, int n_in,
                              void* d_out, int out_size, void* d_ws, size_t ws_size,
                              hipStream_t stream) {
    const float* supp  = (const float*)d_in[0];
    const float* query = (const float*)d_in[1];
    const int*   ys    = (const int*)d_in[2];
    float* out = (float*)d_out;

    float* ws  = (float*)d_ws;
    float* sp  = ws;                       // 10240
    float* sn  = ws + 10240;               // 8
    float* num = ws + 10248;               // 2560
    float* sq  = ws + 12808;               // 512

    supp_pool_kernel<<<S_DIM, 512, 0, stream>>>(supp, sp, sn);
    query_pool_dot_kernel<<<Q_DIM, 512, 0, stream>>>(query, sp, num, sq);
    finalize_kernel<<<1, 512, 0, stream>>>(num, sq, sn, ys, out);
}